// Round 2
// baseline (314.611 us; speedup 1.0000x reference)
//
#include <hip/hip_runtime.h>
#include <math.h>

// Problem constants
#define NREL 499        // 2*MAX_LEN-1
#define NREL_PAD 500    // row stride for qrel (2000 B, 16-B aligned)
#define LDB 72          // bf16 LDS row stride (flash kernel)

typedef __attribute__((ext_vector_type(8))) short bf16x8;
typedef __attribute__((ext_vector_type(4))) float f32x4;

__device__ __forceinline__ float bf2f(ushort x) {
  union { unsigned u; float f; } v; v.u = ((unsigned)x) << 16; return v.f;
}
__device__ __forceinline__ ushort f2bf(float x) {
  union { float f; unsigned u; } v; v.f = x;
  return (ushort)((v.u + 0x8000u) >> 16);
}
__device__ __forceinline__ bf16x8 pack8(float4 a, float4 b) {
  bf16x8 r;
  r[0] = (short)f2bf(a.x); r[1] = (short)f2bf(a.y);
  r[2] = (short)f2bf(a.z); r[3] = (short)f2bf(a.w);
  r[4] = (short)f2bf(b.x); r[5] = (short)f2bf(b.y);
  r[6] = (short)f2bf(b.z); r[7] = (short)f2bf(b.w);
  return r;
}

// ============================================================================
// prep_wt: Wt[z][n][k] (bf16) = W_z[k][n], z = {q,k,v,o}. Grid (8,8,4).
// ============================================================================
__global__ __launch_bounds__(256) void prep_wt(const float* __restrict__ W0,
                                               const float* __restrict__ W1,
                                               const float* __restrict__ W2,
                                               const float* __restrict__ W3,
                                               ushort* __restrict__ Wt) {
  __shared__ float T[64][68];
  const int t = threadIdx.x;
  const int k0 = blockIdx.x * 64, n0 = blockIdx.y * 64, z = blockIdx.z;
  const float* W = (z == 0) ? W0 : (z == 1) ? W1 : (z == 2) ? W2 : W3;
#pragma unroll
  for (int s = 0; s < 4; ++s) {
    int idx = t + s * 256;
    int r = idx >> 4, c4 = (idx & 15) << 2;
    *(float4*)&T[r][c4] = *(const float4*)(W + (size_t)(k0 + r) * 512 + n0 + c4);
  }
  __syncthreads();
#pragma unroll
  for (int s = 0; s < 4; ++s) {
    int idx = t + s * 256;
    int row = idx >> 4, c4 = (idx & 15) << 2;  // row = n_local, c4 = k_local
    ushort4 u = make_ushort4(f2bf(T[c4 + 0][row]), f2bf(T[c4 + 1][row]),
                             f2bf(T[c4 + 2][row]), f2bf(T[c4 + 3][row]));
    *(ushort4*)(Wt + (size_t)z * 262144 + (size_t)(n0 + row) * 512 + k0 + c4) = u;
  }
}

// ============================================================================
// gemm_body: C[4096x512] = A(fp32) @ Wt^T(bf16 [n][k]) + bias. No LDS; A/W
// fragments straight from global (Wt L2-resident). Tile 64x64, 4 waves.
// MODE 0: fp32 row-major out [4096][512]               (output projection)
// MODE 1: bf16 Vt [bh][64 d][2048 l] (operands swapped -> coalesced stores)
// MODE 2: bf16 row-major head-split [bh][2048 l][64 d] (Q, K)
// ============================================================================
template <int MODE>
__device__ __forceinline__ void gemm_body(const float* __restrict__ A,
                                          const ushort* __restrict__ Wt,
                                          const float* __restrict__ bias,
                                          void* __restrict__ outv,
                                          int bx, int by) {
  const int t = threadIdx.x;
  const int lane = t & 63, wave = t >> 6;
  const int m16 = lane & 15, quad = lane >> 4;
  const int i0 = by * 64;
  const int n0 = bx * 64;
  f32x4 acc[4] = {{0.f, 0.f, 0.f, 0.f}, {0.f, 0.f, 0.f, 0.f},
                  {0.f, 0.f, 0.f, 0.f}, {0.f, 0.f, 0.f, 0.f}};

  if (MODE != 1) {
    // D rows = i (wave strip), cols = n. acc[nt]: n-subtile nt.
    const float* arow = A + (size_t)(i0 + (wave << 4) + m16) * 512 + (quad << 3);
#pragma unroll 4
    for (int kc = 0; kc < 16; ++kc) {
      float4 a0 = *(const float4*)(arow + kc * 32);
      float4 a1 = *(const float4*)(arow + kc * 32 + 4);
      bf16x8 af = pack8(a0, a1);
#pragma unroll
      for (int nt = 0; nt < 4; ++nt) {
        bf16x8 wf = *(const bf16x8*)(Wt + (size_t)(n0 + (nt << 4) + m16) * 512 +
                                     kc * 32 + (quad << 3));
        acc[nt] = __builtin_amdgcn_mfma_f32_16x16x32_bf16(af, wf, acc[nt], 0, 0, 0);
      }
    }
  } else {
    // D rows = n (wave strip), cols = i. acc[it]: i-subtile it.
    const ushort* wrow = Wt + (size_t)(n0 + (wave << 4) + m16) * 512 + (quad << 3);
#pragma unroll 2
    for (int kc = 0; kc < 16; ++kc) {
      bf16x8 wf = *(const bf16x8*)(wrow + kc * 32);
#pragma unroll
      for (int it = 0; it < 4; ++it) {
        const float* ap = A + (size_t)(i0 + (it << 4) + m16) * 512 + kc * 32 + (quad << 3);
        bf16x8 af = pack8(*(const float4*)ap, *(const float4*)(ap + 4));
        acc[it] = __builtin_amdgcn_mfma_f32_16x16x32_bf16(wf, af, acc[it], 0, 0, 0);
      }
    }
  }

  if (MODE == 0) {
    float* out = (float*)outv;
#pragma unroll
    for (int nt = 0; nt < 4; ++nt) {
      float bn = bias[n0 + (nt << 4) + m16];
#pragma unroll
      for (int r = 0; r < 4; ++r) {
        int i = i0 + (wave << 4) + (quad << 2) + r;
        out[(size_t)i * 512 + n0 + (nt << 4) + m16] = acc[nt][r] + bn;
      }
    }
  } else if (MODE == 2) {
    ushort* out = (ushort*)outv;
    const int b = i0 >> 11, l0 = i0 & 2047, h = n0 >> 6;
#pragma unroll
    for (int nt = 0; nt < 4; ++nt) {
      float bn = bias[n0 + (nt << 4) + m16];
      int d = (nt << 4) + m16;
#pragma unroll
      for (int r = 0; r < 4; ++r) {
        int il = (wave << 4) + (quad << 2) + r;
        out[((size_t)(b * 8 + h) * 2048 + l0 + il) * 64 + d] = f2bf(acc[nt][r] + bn);
      }
    }
  } else {  // MODE 1: Vt [bh][d][l]
    ushort* out = (ushort*)outv;
    const int b = i0 >> 11, l0 = i0 & 2047, h = n0 >> 6;
    float4 b4 = *(const float4*)(bias + n0 + (wave << 4) + (quad << 2));
    float bb[4] = {b4.x, b4.y, b4.z, b4.w};
#pragma unroll
    for (int r = 0; r < 4; ++r) {
      int d = (wave << 4) + (quad << 2) + r;
#pragma unroll
      for (int it = 0; it < 4; ++it) {
        out[((size_t)(b * 8 + h) * 64 + d) * 2048 + l0 + (it << 4) + m16] =
            f2bf(acc[it][r] + bb[r]);
      }
    }
  }
}

template <int MODE>
__global__ __launch_bounds__(256) void gemm_mfma(const float* __restrict__ A,
                                                 const ushort* __restrict__ Wt,
                                                 const float* __restrict__ bias,
                                                 void* __restrict__ outv) {
  gemm_body<MODE>(A, Wt, bias, outv, blockIdx.x, blockIdx.y);
}

// Merged QKV projection: grid (8, 64, 3) -> 1536 blocks (6/CU).
__global__ __launch_bounds__(256) void gemm_qkv(
    const float* __restrict__ q, const float* __restrict__ k,
    const float* __restrict__ v, const ushort* __restrict__ Wt,
    const float* __restrict__ bq, const float* __restrict__ bk,
    const float* __restrict__ bv, ushort* __restrict__ Qw,
    ushort* __restrict__ Kw, ushort* __restrict__ Vtw) {
  const int z = blockIdx.z;
  if (z == 0) {
    gemm_body<2>(q, Wt, bq, (void*)Qw, blockIdx.x, blockIdx.y);
  } else if (z == 1) {
    gemm_body<2>(k, Wt + 262144, bk, (void*)Kw, blockIdx.x, blockIdx.y);
  } else {
    gemm_body<1>(v, Wt + 2 * 262144, bv, (void*)Vtw, blockIdx.x, blockIdx.y);
  }
}

// ============================================================================
// qrel_mfma: qrel[bh][i][r] = sum_d Q[bh][i][d]*rel[r][d] (fp32 out, stride
// NREL_PAD). MFMA bf16, fragments direct from global. Grid (8, 32, 16).
// ============================================================================
__global__ __launch_bounds__(256) void qrel_mfma(const ushort* __restrict__ Qw,
                                                 const float* __restrict__ rel,
                                                 float* __restrict__ qrel) {
  const int t = threadIdx.x;
  const int lane = t & 63, wave = t >> 6;
  const int m16 = lane & 15, quad = lane >> 4;
  const int r0 = blockIdx.x * 64;
  const int i0 = blockIdx.y * 64;
  const int bh = blockIdx.z;
  const ushort* Qb = Qw + ((size_t)bh * 2048 + i0 + (wave << 4) + m16) * 64;
  bf16x8 qa0 = *(const bf16x8*)(Qb + (quad << 3));
  bf16x8 qa1 = *(const bf16x8*)(Qb + 32 + (quad << 3));

  f32x4 acc[4] = {{0.f, 0.f, 0.f, 0.f}, {0.f, 0.f, 0.f, 0.f},
                  {0.f, 0.f, 0.f, 0.f}, {0.f, 0.f, 0.f, 0.f}};
#pragma unroll
  for (int rt = 0; rt < 4; ++rt) {
    int rr = min(r0 + (rt << 4) + m16, NREL - 1);
    const float* rp = rel + (size_t)rr * 64 + (quad << 3);
    bf16x8 rf0 = pack8(*(const float4*)rp, *(const float4*)(rp + 4));
    bf16x8 rf1 = pack8(*(const float4*)(rp + 32), *(const float4*)(rp + 36));
    acc[rt] = __builtin_amdgcn_mfma_f32_16x16x32_bf16(qa0, rf0, acc[rt], 0, 0, 0);
    acc[rt] = __builtin_amdgcn_mfma_f32_16x16x32_bf16(qa1, rf1, acc[rt], 0, 0, 0);
  }
#pragma unroll
  for (int rt = 0; rt < 4; ++rt) {
    int r = r0 + (rt << 4) + m16;
    if (r < NREL_PAD) {
#pragma unroll
      for (int rg = 0; rg < 4; ++rg) {
        int i = i0 + (wave << 4) + (quad << 2) + rg;
        qrel[((size_t)bh * 2048 + i) * NREL_PAD + r] = acc[rt][rg];
      }
    }
  }
}

// ============================================================================
// Flash attention, MFMA bf16, software-pipelined prefetch.
// SPLIT=1: grid (32,16,2) — each block handles half the j-range and writes
// unnormalized partials (Opart, m, l); combine_attn merges. Doubles the
// concurrent waves/CU (8 -> 16) on this latency-bound kernel.
// SPLIT=0: original single-pass path (workspace fallback).
// ============================================================================
template <int SPLIT>
__global__ __launch_bounds__(256) void flash_attn(
    const ushort* __restrict__ Qw, const ushort* __restrict__ Kw,
    const ushort* __restrict__ Vt, const float* __restrict__ qrel,
    const int* __restrict__ mask, float* __restrict__ attn,
    float* __restrict__ Opart, float* __restrict__ MLp) {
  __shared__ ushort QPs[64 * LDB];  // Q tile [i][d]; later P [i][j]
  __shared__ ushort Ks[64 * LDB];   // [j][d]
  __shared__ ushort Vs[64 * LDB];   // [d][j]
  const int t = threadIdx.x;
  const int lane = t & 63, wave = t >> 6;
  const int m16 = lane & 15, quad = lane >> 4;
  const int koff = quad << 3;
  const int i0 = blockIdx.x * 64;
  const int bh = blockIdx.y;
  const int b = bh >> 3, h = bh & 7;
  const int jstart = SPLIT ? ((int)blockIdx.z << 10) : 0;
  const int jend = SPLIT ? (jstart + 1024) : 2048;
  const ushort* Qb = Qw + (size_t)bh * 2048 * 64;
  const ushort* Kb = Kw + (size_t)bh * 2048 * 64;
  const ushort* Vb = Vt + (size_t)bh * 64 * 2048;
  const float* qrl = qrel + (size_t)bh * 2048 * NREL_PAD;
  const int* mb = mask + b * 2048;

  // staging slot for this thread (two uint4 per thread per buffer)
  const int row0 = t >> 3, off0 = (t & 7) << 3;
  const int row1 = (t + 256) >> 3, off1 = ((t + 256) & 7) << 3;

  // Q tile -> LDS
  *(uint4*)&QPs[row0 * LDB + off0] =
      *(const uint4*)(Qb + (size_t)(i0 + row0) * 64 + off0);
  *(uint4*)&QPs[row1 * LDB + off1] =
      *(const uint4*)(Qb + (size_t)(i0 + row1) * 64 + off1);
  __syncthreads();

  bf16x8 qa0 = *(const bf16x8*)&QPs[((wave << 4) + m16) * LDB + koff];
  bf16x8 qa1 = *(const bf16x8*)&QPs[((wave << 4) + m16) * LDB + 32 + koff];

  const int irow0 = i0 + (wave << 4) + (quad << 2);

  // ---- prologue prefetch for j0 = jstart ----
  uint4 kr0 = *(const uint4*)(Kb + (size_t)(jstart + row0) * 64 + off0);
  uint4 kr1 = *(const uint4*)(Kb + (size_t)(jstart + row1) * 64 + off1);
  uint4 vr0 = *(const uint4*)(Vb + (size_t)row0 * 2048 + jstart + off0);
  uint4 vr1 = *(const uint4*)(Vb + (size_t)row1 * 2048 + jstart + off1);
  float qv[4][4];
  int mk[4];
#pragma unroll
  for (int jt = 0; jt < 4; ++jt) {
    int j = jstart + (jt << 4) + m16;
    mk[jt] = mb[j];
#pragma unroll
    for (int r = 0; r < 4; ++r) {
      int i = irow0 + r;
      int rr = min(NREL - 1, max(0, j - i + (NREL / 2)));
      qv[jt][r] = qrl[(size_t)i * NREL_PAD + rr];
    }
  }

  float m_i[4], l_i[4];
  f32x4 oacc[4];
#pragma unroll
  for (int r = 0; r < 4; ++r) { m_i[r] = -INFINITY; l_i[r] = 0.f; }
#pragma unroll
  for (int dt = 0; dt < 4; ++dt) oacc[dt] = (f32x4){0.f, 0.f, 0.f, 0.f};

  for (int j0 = jstart; j0 < jend; j0 += 64) {
    __syncthreads();
    // stage prefetched K/V regs into LDS
    *(uint4*)&Ks[row0 * LDB + off0] = kr0;
    *(uint4*)&Ks[row1 * LDB + off1] = kr1;
    *(uint4*)&Vs[row0 * LDB + off0] = vr0;
    *(uint4*)&Vs[row1 * LDB + off1] = vr1;
    __syncthreads();

    // ---- issue next-tile prefetch (latency hides under this iter's compute)
    const int jn = (j0 + 64) & 2047;  // wraps on last iter (unused)
    uint4 kn0 = *(const uint4*)(Kb + (size_t)(jn + row0) * 64 + off0);
    uint4 kn1 = *(const uint4*)(Kb + (size_t)(jn + row1) * 64 + off1);
    uint4 vn0 = *(const uint4*)(Vb + (size_t)row0 * 2048 + jn + off0);
    uint4 vn1 = *(const uint4*)(Vb + (size_t)row1 * 2048 + jn + off1);
    float qn[4][4];
    int mkn[4];
#pragma unroll
    for (int jt = 0; jt < 4; ++jt) {
      int j = jn + (jt << 4) + m16;
      mkn[jt] = mb[j];
#pragma unroll
      for (int r = 0; r < 4; ++r) {
        int i = irow0 + r;
        int rr = min(NREL - 1, max(0, j - i + (NREL / 2)));
        qn[jt][r] = qrl[(size_t)i * NREL_PAD + rr];
      }
    }

    // ---- QK^T ----
    f32x4 sacc[4];
    __builtin_amdgcn_s_setprio(1);
#pragma unroll
    for (int jt = 0; jt < 4; ++jt) {
      bf16x8 kb0 = *(const bf16x8*)&Ks[((jt << 4) + m16) * LDB + koff];
      bf16x8 kb1 = *(const bf16x8*)&Ks[((jt << 4) + m16) * LDB + 32 + koff];
      f32x4 z = {0.f, 0.f, 0.f, 0.f};
      z = __builtin_amdgcn_mfma_f32_16x16x32_bf16(qa0, kb0, z, 0, 0, 0);
      z = __builtin_amdgcn_mfma_f32_16x16x32_bf16(qa1, kb1, z, 0, 0, 0);
      sacc[jt] = z;
    }
    __builtin_amdgcn_s_setprio(0);

    // ---- scores: scale + rel-bias (prefetched) + mask (prefetched) ----
    float sv[4][4];
#pragma unroll
    for (int jt = 0; jt < 4; ++jt) {
#pragma unroll
      for (int r = 0; r < 4; ++r) {
        float sc = sacc[jt][r] * 0.125f + qv[jt][r];
        sv[jt][r] = (mk[jt] == 0) ? -1e10f : sc;
      }
    }

    // ---- online softmax ----
    float al[4];
#pragma unroll
    for (int r = 0; r < 4; ++r) {
      float mx = fmaxf(fmaxf(sv[0][r], sv[1][r]), fmaxf(sv[2][r], sv[3][r]));
#pragma unroll
      for (int w = 1; w < 16; w <<= 1) mx = fmaxf(mx, __shfl_xor(mx, w, 16));
      float mnew = fmaxf(m_i[r], mx);
      al[r] = __expf(m_i[r] - mnew);
      float sum = 0.f;
#pragma unroll
      for (int jt = 0; jt < 4; ++jt) {
        float p = __expf(sv[jt][r] - mnew);
        sv[jt][r] = p;
        sum += p;
      }
#pragma unroll
      for (int w = 1; w < 16; w <<= 1) sum += __shfl_xor(sum, w, 16);
      m_i[r] = mnew;
      l_i[r] = l_i[r] * al[r] + sum;
#pragma unroll
      for (int dt = 0; dt < 4; ++dt) oacc[dt][r] *= al[r];
    }

    // ---- P -> LDS (per-wave region; intra-wave consume) ----
    const int prow0 = (wave << 4) + (quad << 2);
#pragma unroll
    for (int jt = 0; jt < 4; ++jt)
#pragma unroll
      for (int r = 0; r < 4; ++r)
        QPs[(prow0 + r) * LDB + (jt << 4) + m16] = f2bf(sv[jt][r]);
    __asm__ volatile("s_waitcnt lgkmcnt(0)" ::: "memory");

    bf16x8 pa0 = *(const bf16x8*)&QPs[((wave << 4) + m16) * LDB + koff];
    bf16x8 pa1 = *(const bf16x8*)&QPs[((wave << 4) + m16) * LDB + 32 + koff];
    __builtin_amdgcn_s_setprio(1);
#pragma unroll
    for (int dt = 0; dt < 4; ++dt) {
      bf16x8 vb0 = *(const bf16x8*)&Vs[((dt << 4) + m16) * LDB + koff];
      bf16x8 vb1 = *(const bf16x8*)&Vs[((dt << 4) + m16) * LDB + 32 + koff];
      oacc[dt] = __builtin_amdgcn_mfma_f32_16x16x32_bf16(pa0, vb0, oacc[dt], 0, 0, 0);
      oacc[dt] = __builtin_amdgcn_mfma_f32_16x16x32_bf16(pa1, vb1, oacc[dt], 0, 0, 0);
    }
    __builtin_amdgcn_s_setprio(0);

    // ---- rotate prefetched state ----
    kr0 = kn0; kr1 = kn1; vr0 = vn0; vr1 = vn1;
#pragma unroll
    for (int jt = 0; jt < 4; ++jt) {
      mk[jt] = mkn[jt];
#pragma unroll
      for (int r = 0; r < 4; ++r) qv[jt][r] = qn[jt][r];
    }
  }

#pragma unroll
  for (int r = 0; r < 4; ++r) {
    int i = irow0 + r;
    if (SPLIT) {
      size_t rb = ((size_t)(((int)blockIdx.z << 4) + bh) * 2048 + i);
      float* dst = Opart + rb * 64;
#pragma unroll
      for (int dt = 0; dt < 4; ++dt) dst[(dt << 4) + m16] = oacc[dt][r];
      if (m16 == 0) { MLp[rb * 2] = m_i[r]; MLp[rb * 2 + 1] = l_i[r]; }
    } else {
      float inv = 1.0f / l_i[r];
      float* dst = attn + (size_t)(b * 2048 + i) * 512 + h * 64;
#pragma unroll
      for (int dt = 0; dt < 4; ++dt) dst[(dt << 4) + m16] = oacc[dt][r] * inv;
    }
  }
}

// ============================================================================
// combine_attn: merge the two j-half partials. Grid (32, 16), 256 thr.
// out[i] = (w0*O0 + w1*O1) / (w0*l0 + w1*l1), wz = exp(mz - max(m0,m1)).
// ============================================================================
__global__ __launch_bounds__(256) void combine_attn(
    const float* __restrict__ Opart, const float* __restrict__ MLp,
    float* __restrict__ attn) {
  const int t = threadIdx.x;
  const int i0 = blockIdx.x * 64, bh = blockIdx.y;
  const int b = bh >> 3, h = bh & 7;
  const int row = t >> 2, d0 = (t & 3) << 4;
  const int i = i0 + row;
  const size_t rb0 = (size_t)bh * 2048 + i;
  const size_t rb1 = (size_t)(16 + bh) * 2048 + i;
  float m0 = MLp[rb0 * 2], l0 = MLp[rb0 * 2 + 1];
  float m1 = MLp[rb1 * 2], l1 = MLp[rb1 * 2 + 1];
  float M = fmaxf(m0, m1);
  float w0 = __expf(m0 - M), w1 = __expf(m1 - M);
  float inv = 1.0f / (w0 * l0 + w1 * l1);
  const float* p0 = Opart + rb0 * 64 + d0;
  const float* p1 = Opart + rb1 * 64 + d0;
  float* dst = attn + ((size_t)(b * 2048) + i) * 512 + h * 64 + d0;
#pragma unroll
  for (int c = 0; c < 4; ++c) {
    float4 a = *(const float4*)(p0 + c * 4);
    float4 bq = *(const float4*)(p1 + c * 4);
    float4 o;
    o.x = (w0 * a.x + w1 * bq.x) * inv;
    o.y = (w0 * a.y + w1 * bq.y) * inv;
    o.z = (w0 * a.z + w1 * bq.z) * inv;
    o.w = (w0 * a.w + w1 * bq.w) * inv;
    *(float4*)(dst + c * 4) = o;
  }
}

// ============================================================================
extern "C" void kernel_launch(void* const* d_in, const int* in_sizes, int n_in,
                              void* d_out, int out_size, void* d_ws,
                              size_t ws_size, hipStream_t stream) {
  const float* query = (const float*)d_in[0];
  const float* key   = (const float*)d_in[1];
  const float* value = (const float*)d_in[2];
  const int*   mask  = (const int*)d_in[3];
  const float* Wq = (const float*)d_in[4];
  const float* bq = (const float*)d_in[5];
  const float* Wk = (const float*)d_in[6];
  const float* bk = (const float*)d_in[7];
  const float* Wv = (const float*)d_in[8];
  const float* bv = (const float*)d_in[9];
  const float* Wo = (const float*)d_in[10];
  const float* bo = (const float*)d_in[11];
  const float* rel = (const float*)d_in[12];

  char* w = (char*)d_ws;
  size_t off = 0;
  ushort* Qw  = (ushort*)(w + off); off += (size_t)16 * 2048 * 64 * 2;       // 4 MB
  ushort* Kw  = (ushort*)(w + off); off += (size_t)16 * 2048 * 64 * 2;       // 4 MB
  ushort* Vtw = (ushort*)(w + off); off += (size_t)16 * 64 * 2048 * 2;       // 4 MB
  ushort* Wt  = (ushort*)(w + off); off += (size_t)4 * 512 * 512 * 2;        // 2 MB
  float* qrel = (float*)(w + off);  off += (size_t)16 * 2048 * NREL_PAD * 4; // 65.5 MB
  float* attn = (float*)(w + off);  off += (size_t)4096 * 512 * 4;           // 8 MB
  float* Opart = (float*)(w + off); off += (size_t)2 * 16 * 2048 * 64 * 4;   // 16 MB
  float* MLp  = (float*)(w + off);  off += (size_t)2 * 16 * 2048 * 2 * 4;    // 1 MB
  float* out = (float*)d_out;
  const bool split = (ws_size >= off);

  dim3 bb(256);
  hipLaunchKernelGGL(prep_wt, dim3(8, 8, 4), bb, 0, stream, Wq, Wk, Wv, Wo, Wt);
  hipLaunchKernelGGL(gemm_qkv, dim3(8, 64, 3), bb, 0, stream, query, key, value,
                     Wt, bq, bk, bv, Qw, Kw, Vtw);
  hipLaunchKernelGGL(qrel_mfma, dim3(8, 32, 16), bb, 0, stream, Qw, rel, qrel);
  if (split) {
    hipLaunchKernelGGL((flash_attn<1>), dim3(32, 16, 2), bb, 0, stream, Qw, Kw,
                       Vtw, qrel, mask, attn, Opart, MLp);
    hipLaunchKernelGGL(combine_attn, dim3(32, 16), bb, 0, stream, Opart, MLp,
                       attn);
  } else {
    hipLaunchKernelGGL((flash_attn<0>), dim3(32, 16), bb, 0, stream, Qw, Kw,
                       Vtw, qrel, mask, attn, attn, attn);
  }
  hipLaunchKernelGGL((gemm_mfma<0>), dim3(8, 64), bb, 0, stream, attn,
                     Wt + 3 * 262144, bo, (void*)out);
}

// Round 3
// 303.109 us; speedup vs baseline: 1.0379x; 1.0379x over previous
//
#include <hip/hip_runtime.h>
#include <math.h>

// Problem constants
#define NREL 499        // 2*MAX_LEN-1
#define NREL_PAD 500    // row stride for qrel (2000 B, 16-B aligned)
#define LDB 72          // bf16 LDS row stride (flash kernel)

typedef __attribute__((ext_vector_type(8))) short bf16x8;
typedef __attribute__((ext_vector_type(4))) float f32x4;

__device__ __forceinline__ float bf2f(ushort x) {
  union { unsigned u; float f; } v; v.u = ((unsigned)x) << 16; return v.f;
}
__device__ __forceinline__ ushort f2bf(float x) {
  union { float f; unsigned u; } v; v.f = x;
  return (ushort)((v.u + 0x8000u) >> 16);
}
__device__ __forceinline__ bf16x8 pack8(float4 a, float4 b) {
  bf16x8 r;
  r[0] = (short)f2bf(a.x); r[1] = (short)f2bf(a.y);
  r[2] = (short)f2bf(a.z); r[3] = (short)f2bf(a.w);
  r[4] = (short)f2bf(b.x); r[5] = (short)f2bf(b.y);
  r[6] = (short)f2bf(b.z); r[7] = (short)f2bf(b.w);
  return r;
}

// ============================================================================
// prep_wt: Wt[z][n][k] (bf16) = W_z[k][n], z = {q,k,v,o}. Grid (8,8,4).
// Blocks (0,0,z) additionally build maskbf[b][j] = mask ? 1.0bf : 0.0bf.
// ============================================================================
__global__ __launch_bounds__(256) void prep_wt(const float* __restrict__ W0,
                                               const float* __restrict__ W1,
                                               const float* __restrict__ W2,
                                               const float* __restrict__ W3,
                                               const int* __restrict__ mask,
                                               ushort* __restrict__ Wt,
                                               ushort* __restrict__ maskbf) {
  __shared__ float T[64][68];
  const int t = threadIdx.x;
  const int k0 = blockIdx.x * 64, n0 = blockIdx.y * 64, z = blockIdx.z;
  const float* W = (z == 0) ? W0 : (z == 1) ? W1 : (z == 2) ? W2 : W3;
#pragma unroll
  for (int s = 0; s < 4; ++s) {
    int idx = t + s * 256;
    int r = idx >> 4, c4 = (idx & 15) << 2;
    *(float4*)&T[r][c4] = *(const float4*)(W + (size_t)(k0 + r) * 512 + n0 + c4);
  }
  if (blockIdx.x == 0 && blockIdx.y == 0) {
    // 4096 mask entries, 4 z-blocks x 256 thr x 4 each
    int base = z * 1024 + t * 4;
    int4 mv = *(const int4*)(mask + base);
    ushort4 mo;
    mo.x = mv.x ? 0x3F80 : 0; mo.y = mv.y ? 0x3F80 : 0;
    mo.z = mv.z ? 0x3F80 : 0; mo.w = mv.w ? 0x3F80 : 0;
    *(ushort4*)(maskbf + base) = mo;
  }
  __syncthreads();
#pragma unroll
  for (int s = 0; s < 4; ++s) {
    int idx = t + s * 256;
    int row = idx >> 4, c4 = (idx & 15) << 2;  // row = n_local, c4 = k_local
    ushort4 u = make_ushort4(f2bf(T[c4 + 0][row]), f2bf(T[c4 + 1][row]),
                             f2bf(T[c4 + 2][row]), f2bf(T[c4 + 3][row]));
    *(ushort4*)(Wt + (size_t)z * 262144 + (size_t)(n0 + row) * 512 + k0 + c4) = u;
  }
}

// ============================================================================
// gemm_body: C[4096x512] = A(fp32) @ Wt^T(bf16 [n][k]) + bias. No LDS.
// MODE 0: fp32 row-major out [4096][512]               (output projection)
// MODE 1: bf16 Vt [bh][64 d][2048 l], masked columns zeroed (mvec)
// MODE 2: bf16 row-major head-split [bh][2048 l][64 d] (Q, K)
// ============================================================================
template <int MODE>
__device__ __forceinline__ void gemm_body(const float* __restrict__ A,
                                          const ushort* __restrict__ Wt,
                                          const float* __restrict__ bias,
                                          const int* __restrict__ mvec,
                                          void* __restrict__ outv,
                                          int bx, int by) {
  const int t = threadIdx.x;
  const int lane = t & 63, wave = t >> 6;
  const int m16 = lane & 15, quad = lane >> 4;
  const int i0 = by * 64;
  const int n0 = bx * 64;
  f32x4 acc[4] = {{0.f, 0.f, 0.f, 0.f}, {0.f, 0.f, 0.f, 0.f},
                  {0.f, 0.f, 0.f, 0.f}, {0.f, 0.f, 0.f, 0.f}};

  if (MODE != 1) {
    const float* arow = A + (size_t)(i0 + (wave << 4) + m16) * 512 + (quad << 3);
#pragma unroll 4
    for (int kc = 0; kc < 16; ++kc) {
      float4 a0 = *(const float4*)(arow + kc * 32);
      float4 a1 = *(const float4*)(arow + kc * 32 + 4);
      bf16x8 af = pack8(a0, a1);
#pragma unroll
      for (int nt = 0; nt < 4; ++nt) {
        bf16x8 wf = *(const bf16x8*)(Wt + (size_t)(n0 + (nt << 4) + m16) * 512 +
                                     kc * 32 + (quad << 3));
        acc[nt] = __builtin_amdgcn_mfma_f32_16x16x32_bf16(af, wf, acc[nt], 0, 0, 0);
      }
    }
  } else {
    const ushort* wrow = Wt + (size_t)(n0 + (wave << 4) + m16) * 512 + (quad << 3);
#pragma unroll 2
    for (int kc = 0; kc < 16; ++kc) {
      bf16x8 wf = *(const bf16x8*)(wrow + kc * 32);
#pragma unroll
      for (int it = 0; it < 4; ++it) {
        const float* ap = A + (size_t)(i0 + (it << 4) + m16) * 512 + kc * 32 + (quad << 3);
        bf16x8 af = pack8(*(const float4*)ap, *(const float4*)(ap + 4));
        acc[it] = __builtin_amdgcn_mfma_f32_16x16x32_bf16(wf, af, acc[it], 0, 0, 0);
      }
    }
  }

  if (MODE == 0) {
    float* out = (float*)outv;
#pragma unroll
    for (int nt = 0; nt < 4; ++nt) {
      float bn = bias[n0 + (nt << 4) + m16];
#pragma unroll
      for (int r = 0; r < 4; ++r) {
        int i = i0 + (wave << 4) + (quad << 2) + r;
        out[(size_t)i * 512 + n0 + (nt << 4) + m16] = acc[nt][r] + bn;
      }
    }
  } else if (MODE == 2) {
    ushort* out = (ushort*)outv;
    const int b = i0 >> 11, l0 = i0 & 2047, h = n0 >> 6;
#pragma unroll
    for (int nt = 0; nt < 4; ++nt) {
      float bn = bias[n0 + (nt << 4) + m16];
      int d = (nt << 4) + m16;
#pragma unroll
      for (int r = 0; r < 4; ++r) {
        int il = (wave << 4) + (quad << 2) + r;
        out[((size_t)(b * 8 + h) * 2048 + l0 + il) * 64 + d] = f2bf(acc[nt][r] + bn);
      }
    }
  } else {  // MODE 1: Vt [bh][d][l], masked columns -> 0
    ushort* out = (ushort*)outv;
    const int b = i0 >> 11, l0 = i0 & 2047, h = n0 >> 6;
    float4 b4 = *(const float4*)(bias + n0 + (wave << 4) + (quad << 2));
    float bb[4] = {b4.x, b4.y, b4.z, b4.w};
    float mkf[4];
#pragma unroll
    for (int it = 0; it < 4; ++it)
      mkf[it] = (mvec[b * 2048 + l0 + (it << 4) + m16] != 0) ? 1.f : 0.f;
#pragma unroll
    for (int r = 0; r < 4; ++r) {
      int d = (wave << 4) + (quad << 2) + r;
#pragma unroll
      for (int it = 0; it < 4; ++it) {
        out[((size_t)(b * 8 + h) * 64 + d) * 2048 + l0 + (it << 4) + m16] =
            f2bf((acc[it][r] + bb[r]) * mkf[it]);
      }
    }
  }
}

template <int MODE>
__global__ __launch_bounds__(256) void gemm_mfma(const float* __restrict__ A,
                                                 const ushort* __restrict__ Wt,
                                                 const float* __restrict__ bias,
                                                 void* __restrict__ outv) {
  gemm_body<MODE>(A, Wt, bias, nullptr, outv, blockIdx.x, blockIdx.y);
}

// Merged QKV projection: grid (8, 64, 3) -> 1536 blocks (6/CU).
__global__ __launch_bounds__(256) void gemm_qkv(
    const float* __restrict__ q, const float* __restrict__ k,
    const float* __restrict__ v, const ushort* __restrict__ Wt,
    const float* __restrict__ bq, const float* __restrict__ bk,
    const float* __restrict__ bv, const int* __restrict__ mask,
    ushort* __restrict__ Qw, ushort* __restrict__ Kw, ushort* __restrict__ Vtw) {
  const int z = blockIdx.z;
  if (z == 0) {
    gemm_body<2>(q, Wt, bq, nullptr, (void*)Qw, blockIdx.x, blockIdx.y);
  } else if (z == 1) {
    gemm_body<2>(k, Wt + 262144, bk, nullptr, (void*)Kw, blockIdx.x, blockIdx.y);
  } else {
    gemm_body<1>(v, Wt + 2 * 262144, bv, mask, (void*)Vtw, blockIdx.x, blockIdx.y);
  }
}

// ============================================================================
// qrel_mfma: qrel[bh][i][r] = sum_d Q[bh][i][d]*rel[r][d] (fp32 out, stride
// NREL_PAD). MFMA bf16, fragments direct from global. Grid (8, 32, 16).
// ============================================================================
__global__ __launch_bounds__(256) void qrel_mfma(const ushort* __restrict__ Qw,
                                                 const float* __restrict__ rel,
                                                 float* __restrict__ qrel) {
  const int t = threadIdx.x;
  const int lane = t & 63, wave = t >> 6;
  const int m16 = lane & 15, quad = lane >> 4;
  const int r0 = blockIdx.x * 64;
  const int i0 = blockIdx.y * 64;
  const int bh = blockIdx.z;
  const ushort* Qb = Qw + ((size_t)bh * 2048 + i0 + (wave << 4) + m16) * 64;
  bf16x8 qa0 = *(const bf16x8*)(Qb + (quad << 3));
  bf16x8 qa1 = *(const bf16x8*)(Qb + 32 + (quad << 3));

  f32x4 acc[4] = {{0.f, 0.f, 0.f, 0.f}, {0.f, 0.f, 0.f, 0.f},
                  {0.f, 0.f, 0.f, 0.f}, {0.f, 0.f, 0.f, 0.f}};
#pragma unroll
  for (int rt = 0; rt < 4; ++rt) {
    int rr = min(r0 + (rt << 4) + m16, NREL - 1);
    const float* rp = rel + (size_t)rr * 64 + (quad << 3);
    bf16x8 rf0 = pack8(*(const float4*)rp, *(const float4*)(rp + 4));
    bf16x8 rf1 = pack8(*(const float4*)(rp + 32), *(const float4*)(rp + 36));
    acc[rt] = __builtin_amdgcn_mfma_f32_16x16x32_bf16(qa0, rf0, acc[rt], 0, 0, 0);
    acc[rt] = __builtin_amdgcn_mfma_f32_16x16x32_bf16(qa1, rf1, acc[rt], 0, 0, 0);
  }
#pragma unroll
  for (int rt = 0; rt < 4; ++rt) {
    int r = r0 + (rt << 4) + m16;
    if (r < NREL_PAD) {
#pragma unroll
      for (int rg = 0; rg < 4; ++rg) {
        int i = i0 + (wave << 4) + (quad << 2) + rg;
        qrel[((size_t)bh * 2048 + i) * NREL_PAD + r] = acc[rt][rg];
      }
    }
  }
}

// ============================================================================
// qrel gather for one 64-j tile; wave-uniform clamp shortcut (far-from-
// diagonal tiles read a single edge value per lane instead of 16 gathers).
// ============================================================================
__device__ __forceinline__ void gather_qv(float qv[4][4],
                                          const float* __restrict__ qrow,
                                          int iq, int iw0, int j0, int quad) {
  if (j0 - iw0 >= 264) {  // j - i >= 249 for all pairs -> rr = 498
    float e = qrow[NREL - 1];
#pragma unroll
    for (int jt = 0; jt < 4; ++jt)
#pragma unroll
      for (int r = 0; r < 4; ++r) qv[jt][r] = e;
  } else if (iw0 - j0 >= 312) {  // i - j >= 249 for all pairs -> rr = 0
    float e = qrow[0];
#pragma unroll
    for (int jt = 0; jt < 4; ++jt)
#pragma unroll
      for (int r = 0; r < 4; ++r) qv[jt][r] = e;
  } else {
#pragma unroll
    for (int jt = 0; jt < 4; ++jt) {
#pragma unroll
      for (int r = 0; r < 4; ++r) {
        int j = j0 + (jt << 4) + (quad << 2) + r;
        int rr = min(NREL - 1, max(0, j - iq + (NREL / 2)));
        qv[jt][r] = qrow[rr];
      }
    }
  }
}

// ============================================================================
// Flash attention, MFMA bf16, swapped-operand QK^T (S^T per lane):
//  - lane (m16=i) holds a 16-wide j-slice of row i -> softmax max is
//    in-register + 2 shfl_xor (cross-quad); no 16-lane shuffle trees.
//  - l_i accumulated by MFMA with a maskf (1/0 bf16) A-fragment: this also
//    applies the key-padding mask to the denominator. Numerator masking is
//    via zeroed Vt columns (gemm MODE 1). Masked scores may enter the
//    running max (softmax invariant to any m >= true max).
//  - P stored as 4x ds_write_b64, read back as A/B frag for PV (swapped):
//    oacc holds O^T -> 4x float4 epilogue stores.
// ============================================================================
__global__ __launch_bounds__(256) void flash_attn(
    const ushort* __restrict__ Qw, const ushort* __restrict__ Kw,
    const ushort* __restrict__ Vt, const float* __restrict__ qrel,
    const ushort* __restrict__ maskbf, float* __restrict__ attn) {
  __shared__ ushort QPs[64 * LDB];  // Q tile [i][d]; later P [i][j]
  __shared__ ushort Ks[64 * LDB];   // [j][d]
  __shared__ ushort Vs[64 * LDB];   // [d][j]
  const int t = threadIdx.x;
  const int lane = t & 63, wave = t >> 6;
  const int m16 = lane & 15, quad = lane >> 4;
  const int koff = quad << 3;
  const int i0 = blockIdx.x * 64;
  const int bh = blockIdx.y;
  const int b = bh >> 3, h = bh & 7;
  const ushort* Qb = Qw + (size_t)bh * 2048 * 64;
  const ushort* Kb = Kw + (size_t)bh * 2048 * 64;
  const ushort* Vb = Vt + (size_t)bh * 64 * 2048;
  const ushort* mbf = maskbf + b * 2048;
  const int iw0 = i0 + (wave << 4);
  const int iq = iw0 + m16;  // this lane's output row
  const float* qrow = qrel + ((size_t)bh * 2048 + iq) * NREL_PAD;

  // staging slot for this thread (two uint4 per thread per buffer)
  const int row0 = t >> 3, off0 = (t & 7) << 3;
  const int row1 = (t + 256) >> 3, off1 = ((t + 256) & 7) << 3;

  // Q tile -> LDS
  *(uint4*)&QPs[row0 * LDB + off0] =
      *(const uint4*)(Qb + (size_t)(i0 + row0) * 64 + off0);
  *(uint4*)&QPs[row1 * LDB + off1] =
      *(const uint4*)(Qb + (size_t)(i0 + row1) * 64 + off1);
  __syncthreads();

  bf16x8 qa0 = *(const bf16x8*)&QPs[((wave << 4) + m16) * LDB + koff];
  bf16x8 qa1 = *(const bf16x8*)&QPs[((wave << 4) + m16) * LDB + 32 + koff];

  // ---- prologue prefetch for j0 = 0 ----
  uint4 kr0 = *(const uint4*)(Kb + (size_t)row0 * 64 + off0);
  uint4 kr1 = *(const uint4*)(Kb + (size_t)row1 * 64 + off1);
  uint4 vr0 = *(const uint4*)(Vb + (size_t)row0 * 2048 + off0);
  uint4 vr1 = *(const uint4*)(Vb + (size_t)row1 * 2048 + off1);
  bf16x8 mfr0 = *(const bf16x8*)(mbf + koff);
  bf16x8 mfr1 = *(const bf16x8*)(mbf + 32 + koff);
  float qv[4][4];
  gather_qv(qv, qrow, iq, iw0, 0, quad);

  float m_i = -INFINITY;
  f32x4 oacc[4];
  f32x4 lacc = {0.f, 0.f, 0.f, 0.f};
#pragma unroll
  for (int dt = 0; dt < 4; ++dt) oacc[dt] = (f32x4){0.f, 0.f, 0.f, 0.f};

  for (int j0 = 0; j0 < 2048; j0 += 64) {
    __syncthreads();
    // stage prefetched K/V regs into LDS
    *(uint4*)&Ks[row0 * LDB + off0] = kr0;
    *(uint4*)&Ks[row1 * LDB + off1] = kr1;
    *(uint4*)&Vs[row0 * LDB + off0] = vr0;
    *(uint4*)&Vs[row1 * LDB + off1] = vr1;
    __syncthreads();

    // ---- issue next-tile prefetch (latency hides under this iter's compute)
    const int jn = (j0 + 64) & 2047;  // wraps on last iter (unused)
    uint4 kn0 = *(const uint4*)(Kb + (size_t)(jn + row0) * 64 + off0);
    uint4 kn1 = *(const uint4*)(Kb + (size_t)(jn + row1) * 64 + off1);
    uint4 vn0 = *(const uint4*)(Vb + (size_t)row0 * 2048 + jn + off0);
    uint4 vn1 = *(const uint4*)(Vb + (size_t)row1 * 2048 + jn + off1);
    bf16x8 mfn0 = *(const bf16x8*)(mbf + jn + koff);
    bf16x8 mfn1 = *(const bf16x8*)(mbf + jn + 32 + koff);
    float qn[4][4];
    gather_qv(qn, qrow, iq, iw0, jn, quad);

    // ---- QK^T, swapped: sacc[jt][r] = S[i = iq][j = j0 + jt*16 + quad*4 + r]
    f32x4 sacc[4];
    __builtin_amdgcn_s_setprio(1);
#pragma unroll
    for (int jt = 0; jt < 4; ++jt) {
      bf16x8 kb0 = *(const bf16x8*)&Ks[((jt << 4) + m16) * LDB + koff];
      bf16x8 kb1 = *(const bf16x8*)&Ks[((jt << 4) + m16) * LDB + 32 + koff];
      f32x4 z = {0.f, 0.f, 0.f, 0.f};
      z = __builtin_amdgcn_mfma_f32_16x16x32_bf16(kb0, qa0, z, 0, 0, 0);
      z = __builtin_amdgcn_mfma_f32_16x16x32_bf16(kb1, qa1, z, 0, 0, 0);
      sacc[jt] = z;
    }
    __builtin_amdgcn_s_setprio(0);

    // ---- scores (no mask injection needed) ----
    float sv[4][4];
#pragma unroll
    for (int jt = 0; jt < 4; ++jt)
#pragma unroll
      for (int r = 0; r < 4; ++r)
        sv[jt][r] = sacc[jt][r] * 0.125f + qv[jt][r];

    // ---- online softmax: in-register 16-max + 2 cross-quad shfl ----
    float t0 = fmaxf(fmaxf(sv[0][0], sv[0][1]), fmaxf(sv[0][2], sv[0][3]));
    float t1 = fmaxf(fmaxf(sv[1][0], sv[1][1]), fmaxf(sv[1][2], sv[1][3]));
    float t2 = fmaxf(fmaxf(sv[2][0], sv[2][1]), fmaxf(sv[2][2], sv[2][3]));
    float t3 = fmaxf(fmaxf(sv[3][0], sv[3][1]), fmaxf(sv[3][2], sv[3][3]));
    float mx = fmaxf(fmaxf(t0, t1), fmaxf(t2, t3));
    mx = fmaxf(mx, __shfl_xor(mx, 16));
    mx = fmaxf(mx, __shfl_xor(mx, 32));
    float mnew = fmaxf(m_i, mx);
    float al = __expf(m_i - mnew);
    m_i = mnew;

    // ---- P = exp(sv - mnew), pack, store as b64 runs (consecutive j) ----
    const int prow = ((wave << 4) + m16) * LDB;
#pragma unroll
    for (int jt = 0; jt < 4; ++jt) {
      ushort4 pk;
      pk.x = f2bf(__expf(sv[jt][0] - mnew));
      pk.y = f2bf(__expf(sv[jt][1] - mnew));
      pk.z = f2bf(__expf(sv[jt][2] - mnew));
      pk.w = f2bf(__expf(sv[jt][3] - mnew));
      *(ushort4*)&QPs[prow + (jt << 4) + (quad << 2)] = pk;
    }

    // ---- rescale accumulators ----
#pragma unroll
    for (int dt = 0; dt < 4; ++dt)
#pragma unroll
      for (int r = 0; r < 4; ++r) oacc[dt][r] *= al;
#pragma unroll
    for (int r = 0; r < 4; ++r) lacc[r] *= al;

    __asm__ volatile("s_waitcnt lgkmcnt(0)" ::: "memory");

    bf16x8 pa0 = *(const bf16x8*)&QPs[prow + koff];
    bf16x8 pa1 = *(const bf16x8*)&QPs[prow + 32 + koff];
    __builtin_amdgcn_s_setprio(1);
    // l_i += sum_j maskf[j] * P[i][j]  (denominator w/ key-padding mask)
    lacc = __builtin_amdgcn_mfma_f32_16x16x32_bf16(mfr0, pa0, lacc, 0, 0, 0);
    lacc = __builtin_amdgcn_mfma_f32_16x16x32_bf16(mfr1, pa1, lacc, 0, 0, 0);
    // O^T[d][i] += Vt[d][j] * P[i][j]  (numerator mask via zeroed Vt cols)
#pragma unroll
    for (int dt = 0; dt < 4; ++dt) {
      bf16x8 vb0 = *(const bf16x8*)&Vs[((dt << 4) + m16) * LDB + koff];
      bf16x8 vb1 = *(const bf16x8*)&Vs[((dt << 4) + m16) * LDB + 32 + koff];
      oacc[dt] = __builtin_amdgcn_mfma_f32_16x16x32_bf16(vb0, pa0, oacc[dt], 0, 0, 0);
      oacc[dt] = __builtin_amdgcn_mfma_f32_16x16x32_bf16(vb1, pa1, oacc[dt], 0, 0, 0);
    }
    __builtin_amdgcn_s_setprio(0);

    // ---- rotate prefetched state ----
    kr0 = kn0; kr1 = kn1; vr0 = vn0; vr1 = vn1;
    mfr0 = mfn0; mfr1 = mfn1;
#pragma unroll
    for (int jt = 0; jt < 4; ++jt)
#pragma unroll
      for (int r = 0; r < 4; ++r) qv[jt][r] = qn[jt][r];
  }

  // epilogue: lane holds O[iq][d = dt*16 + quad*4 + r]; l_i = lacc[0]
  float inv = 1.0f / lacc[0];
  float* dst = attn + (size_t)(b * 2048 + iq) * 512 + h * 64;
#pragma unroll
  for (int dt = 0; dt < 4; ++dt) {
    float4 st;
    st.x = oacc[dt][0] * inv;
    st.y = oacc[dt][1] * inv;
    st.z = oacc[dt][2] * inv;
    st.w = oacc[dt][3] * inv;
    *(float4*)(dst + (dt << 4) + (quad << 2)) = st;
  }
}

// ============================================================================
extern "C" void kernel_launch(void* const* d_in, const int* in_sizes, int n_in,
                              void* d_out, int out_size, void* d_ws,
                              size_t ws_size, hipStream_t stream) {
  const float* query = (const float*)d_in[0];
  const float* key   = (const float*)d_in[1];
  const float* value = (const float*)d_in[2];
  const int*   mask  = (const int*)d_in[3];
  const float* Wq = (const float*)d_in[4];
  const float* bq = (const float*)d_in[5];
  const float* Wk = (const float*)d_in[6];
  const float* bk = (const float*)d_in[7];
  const float* Wv = (const float*)d_in[8];
  const float* bv = (const float*)d_in[9];
  const float* Wo = (const float*)d_in[10];
  const float* bo = (const float*)d_in[11];
  const float* rel = (const float*)d_in[12];

  char* w = (char*)d_ws;
  size_t off = 0;
  ushort* Qw  = (ushort*)(w + off); off += (size_t)16 * 2048 * 64 * 2;       // 4 MB
  ushort* Kw  = (ushort*)(w + off); off += (size_t)16 * 2048 * 64 * 2;       // 4 MB
  ushort* Vtw = (ushort*)(w + off); off += (size_t)16 * 64 * 2048 * 2;       // 4 MB
  ushort* Wt  = (ushort*)(w + off); off += (size_t)4 * 512 * 512 * 2;        // 2 MB
  float* qrel = (float*)(w + off);  off += (size_t)16 * 2048 * NREL_PAD * 4; // 65.5 MB
  float* attn = (float*)(w + off);  off += (size_t)4096 * 512 * 4;           // 8 MB
  ushort* maskbf = (ushort*)(w + off); off += (size_t)2 * 2048 * 2;          // 8 KB
  float* out = (float*)d_out;

  dim3 bb(256);
  hipLaunchKernelGGL(prep_wt, dim3(8, 8, 4), bb, 0, stream, Wq, Wk, Wv, Wo,
                     mask, Wt, maskbf);
  hipLaunchKernelGGL(gemm_qkv, dim3(8, 64, 3), bb, 0, stream, query, key, value,
                     Wt, bq, bk, bv, mask, Qw, Kw, Vtw);
  hipLaunchKernelGGL(qrel_mfma, dim3(8, 32, 16), bb, 0, stream, Qw, rel, qrel);
  hipLaunchKernelGGL(flash_attn, dim3(32, 16), bb, 0, stream, Qw, Kw, Vtw, qrel,
                     maskbf, attn);
  hipLaunchKernelGGL((gemm_mfma<0>), dim3(8, 64), bb, 0, stream, attn,
                     Wt + 3 * 262144, bo, (void*)out);
}

// Round 4
// 232.798 us; speedup vs baseline: 1.3514x; 1.3020x over previous
//
#include <hip/hip_runtime.h>
#include <math.h>

// Problem constants
#define NREL 499        // 2*MAX_LEN-1
#define NREL_PAD 500    // row stride for qrel (2000 B, 16-B aligned)
#define LDB 72          // bf16 LDS row stride (flash kernel)
#define LDT 72          // bf16 LDS row stride (gemm tiles)

typedef __attribute__((ext_vector_type(8))) short bf16x8;
typedef __attribute__((ext_vector_type(4))) float f32x4;

__device__ __forceinline__ float bf2f(ushort x) {
  union { unsigned u; float f; } v; v.u = ((unsigned)x) << 16; return v.f;
}
__device__ __forceinline__ ushort f2bf(float x) {
  union { float f; unsigned u; } v; v.f = x;
  return (ushort)((v.u + 0x8000u) >> 16);
}
__device__ __forceinline__ bf16x8 pack8(float4 a, float4 b) {
  bf16x8 r;
  r[0] = (short)f2bf(a.x); r[1] = (short)f2bf(a.y);
  r[2] = (short)f2bf(a.z); r[3] = (short)f2bf(a.w);
  r[4] = (short)f2bf(b.x); r[5] = (short)f2bf(b.y);
  r[6] = (short)f2bf(b.z); r[7] = (short)f2bf(b.w);
  return r;
}

// ============================================================================
// cast_bf16: q/k/v fp32 [4096][512] -> bf16, contiguous dst. Grid (1024,1,3).
// ============================================================================
__global__ __launch_bounds__(256) void cast_bf16(const float* __restrict__ q,
                                                 const float* __restrict__ k,
                                                 const float* __restrict__ v,
                                                 ushort* __restrict__ dst) {
  const int z = blockIdx.z;
  const float* src = (z == 0) ? q : (z == 1) ? k : v;
  const size_t base = ((size_t)blockIdx.x * 256 + threadIdx.x) * 8;
  float4 a = *(const float4*)(src + base);
  float4 b = *(const float4*)(src + base + 4);
  *(bf16x8*)(dst + (size_t)z * 2097152 + base) = pack8(a, b);
}

// ============================================================================
// prep_wt: Wt[z][n][k] (bf16) = W_z[k][n], z = {q,k,v,o}. Grid (8,8,4).
// Blocks (0,0,z) additionally build maskbf[b][j] = mask ? 1.0bf : 0.0bf.
// ============================================================================
__global__ __launch_bounds__(256) void prep_wt(const float* __restrict__ W0,
                                               const float* __restrict__ W1,
                                               const float* __restrict__ W2,
                                               const float* __restrict__ W3,
                                               const int* __restrict__ mask,
                                               ushort* __restrict__ Wt,
                                               ushort* __restrict__ maskbf) {
  __shared__ float T[64][68];
  const int t = threadIdx.x;
  const int k0 = blockIdx.x * 64, n0 = blockIdx.y * 64, z = blockIdx.z;
  const float* W = (z == 0) ? W0 : (z == 1) ? W1 : (z == 2) ? W2 : W3;
#pragma unroll
  for (int s = 0; s < 4; ++s) {
    int idx = t + s * 256;
    int r = idx >> 4, c4 = (idx & 15) << 2;
    *(float4*)&T[r][c4] = *(const float4*)(W + (size_t)(k0 + r) * 512 + n0 + c4);
  }
  if (blockIdx.x == 0 && blockIdx.y == 0) {
    int base = z * 1024 + t * 4;
    int4 mv = *(const int4*)(mask + base);
    ushort4 mo;
    mo.x = mv.x ? 0x3F80 : 0; mo.y = mv.y ? 0x3F80 : 0;
    mo.z = mv.z ? 0x3F80 : 0; mo.w = mv.w ? 0x3F80 : 0;
    *(ushort4*)(maskbf + base) = mo;
  }
  __syncthreads();
#pragma unroll
  for (int s = 0; s < 4; ++s) {
    int idx = t + s * 256;
    int row = idx >> 4, c4 = (idx & 15) << 2;  // row = n_local, c4 = k_local
    ushort4 u = make_ushort4(f2bf(T[c4 + 0][row]), f2bf(T[c4 + 1][row]),
                             f2bf(T[c4 + 2][row]), f2bf(T[c4 + 3][row]));
    *(ushort4*)(Wt + (size_t)z * 262144 + (size_t)(n0 + row) * 512 + k0 + c4) = u;
  }
}

// ============================================================================
// gemm_tile_body: C[64x64 tile] = A(bf16 [M][512]) @ Wt^T(bf16 [n][k]) + bias.
// LDS-staged (padded stride, conflict-free), register-held next tile
// (flash-style async split), 2 barriers/K-step, 8 K-steps of BK=64.
// MODE 0: fp32 row-major out [4096][512]               (output projection)
// MODE 1: bf16 Vt [bh][64 d][2048 l], masked columns zeroed (mvec)
// MODE 2: bf16 row-major head-split [bh][2048 l][64 d] (Q, K)
// ============================================================================
template <int MODE>
__device__ __forceinline__ void gemm_tile_body(const ushort* __restrict__ A,
                                               const ushort* __restrict__ Wt,
                                               const float* __restrict__ bias,
                                               const int* __restrict__ mvec,
                                               void* __restrict__ outv,
                                               int bx, int by) {
  __shared__ ushort As[64 * LDT];
  __shared__ ushort Bs[64 * LDT];
  const int t = threadIdx.x;
  const int lane = t & 63, wave = t >> 6;
  const int m16 = lane & 15, quad = lane >> 4;
  const int koff = quad << 3;
  const int i0 = by * 64, n0 = bx * 64;
  const int row0 = t >> 3, off0 = (t & 7) << 3;
  const int row1 = (t + 256) >> 3, off1 = ((t + 256) & 7) << 3;
  const ushort* Ab = A + (size_t)i0 * 512;
  const ushort* Bb = Wt + (size_t)n0 * 512;

  // prologue: tile 0 -> regs
  uint4 ar0 = *(const uint4*)(Ab + (size_t)row0 * 512 + off0);
  uint4 ar1 = *(const uint4*)(Ab + (size_t)row1 * 512 + off1);
  uint4 br0 = *(const uint4*)(Bb + (size_t)row0 * 512 + off0);
  uint4 br1 = *(const uint4*)(Bb + (size_t)row1 * 512 + off1);

  f32x4 acc[4] = {{0.f, 0.f, 0.f, 0.f}, {0.f, 0.f, 0.f, 0.f},
                  {0.f, 0.f, 0.f, 0.f}, {0.f, 0.f, 0.f, 0.f}};

  for (int ks = 0; ks < 8; ++ks) {
    __syncthreads();  // previous compute's LDS reads done
    *(uint4*)&As[row0 * LDT + off0] = ar0;
    *(uint4*)&As[row1 * LDT + off1] = ar1;
    *(uint4*)&Bs[row0 * LDT + off0] = br0;
    *(uint4*)&Bs[row1 * LDT + off1] = br1;
    __syncthreads();  // staging visible

    // prefetch next K-step (latency hides under MFMA phase); wraps harmlessly
    const int kn = ((ks + 1) & 7) << 6;
    uint4 an0 = *(const uint4*)(Ab + (size_t)row0 * 512 + kn + off0);
    uint4 an1 = *(const uint4*)(Ab + (size_t)row1 * 512 + kn + off1);
    uint4 bn0 = *(const uint4*)(Bb + (size_t)row0 * 512 + kn + off0);
    uint4 bn1 = *(const uint4*)(Bb + (size_t)row1 * 512 + kn + off1);

    __builtin_amdgcn_s_setprio(1);
    if (MODE != 1) {
#pragma unroll
      for (int kh = 0; kh < 2; ++kh) {
        bf16x8 af = *(const bf16x8*)&As[((wave << 4) + m16) * LDT + (kh << 5) + koff];
#pragma unroll
        for (int nt = 0; nt < 4; ++nt) {
          bf16x8 wf = *(const bf16x8*)&Bs[((nt << 4) + m16) * LDT + (kh << 5) + koff];
          acc[nt] = __builtin_amdgcn_mfma_f32_16x16x32_bf16(af, wf, acc[nt], 0, 0, 0);
        }
      }
    } else {
#pragma unroll
      for (int kh = 0; kh < 2; ++kh) {
        bf16x8 wf = *(const bf16x8*)&Bs[((wave << 4) + m16) * LDT + (kh << 5) + koff];
#pragma unroll
        for (int it = 0; it < 4; ++it) {
          bf16x8 af = *(const bf16x8*)&As[((it << 4) + m16) * LDT + (kh << 5) + koff];
          acc[it] = __builtin_amdgcn_mfma_f32_16x16x32_bf16(wf, af, acc[it], 0, 0, 0);
        }
      }
    }
    __builtin_amdgcn_s_setprio(0);

    ar0 = an0; ar1 = an1; br0 = bn0; br1 = bn1;
  }

  if (MODE == 0) {
    float* out = (float*)outv;
#pragma unroll
    for (int nt = 0; nt < 4; ++nt) {
      float bn = bias[n0 + (nt << 4) + m16];
#pragma unroll
      for (int r = 0; r < 4; ++r) {
        int i = i0 + (wave << 4) + (quad << 2) + r;
        out[(size_t)i * 512 + n0 + (nt << 4) + m16] = acc[nt][r] + bn;
      }
    }
  } else if (MODE == 2) {
    ushort* out = (ushort*)outv;
    const int b = i0 >> 11, l0 = i0 & 2047, h = n0 >> 6;
#pragma unroll
    for (int nt = 0; nt < 4; ++nt) {
      float bn = bias[n0 + (nt << 4) + m16];
      int d = (nt << 4) + m16;
#pragma unroll
      for (int r = 0; r < 4; ++r) {
        int il = (wave << 4) + (quad << 2) + r;
        out[((size_t)(b * 8 + h) * 2048 + l0 + il) * 64 + d] = f2bf(acc[nt][r] + bn);
      }
    }
  } else {  // MODE 1: Vt [bh][d][l], masked columns -> 0
    ushort* out = (ushort*)outv;
    const int b = i0 >> 11, l0 = i0 & 2047, h = n0 >> 6;
    float4 b4 = *(const float4*)(bias + n0 + (wave << 4) + (quad << 2));
    float bb[4] = {b4.x, b4.y, b4.z, b4.w};
    float mkf[4];
#pragma unroll
    for (int it = 0; it < 4; ++it)
      mkf[it] = (mvec[b * 2048 + l0 + (it << 4) + m16] != 0) ? 1.f : 0.f;
#pragma unroll
    for (int r = 0; r < 4; ++r) {
      int d = (wave << 4) + (quad << 2) + r;
#pragma unroll
      for (int it = 0; it < 4; ++it) {
        out[((size_t)(b * 8 + h) * 64 + d) * 2048 + l0 + (it << 4) + m16] =
            f2bf((acc[it][r] + bb[r]) * mkf[it]);
      }
    }
  }
}

template <int MODE>
__global__ __launch_bounds__(256) void gemm_tile(const ushort* __restrict__ A,
                                                 const ushort* __restrict__ Wt,
                                                 const float* __restrict__ bias,
                                                 void* __restrict__ outv) {
  gemm_tile_body<MODE>(A, Wt, bias, nullptr, outv, blockIdx.x, blockIdx.y);
}

// Merged QKV projection: grid (8, 64, 3).
__global__ __launch_bounds__(256) void gemm_qkv(
    const ushort* __restrict__ Abf, const ushort* __restrict__ Wt,
    const float* __restrict__ bq, const float* __restrict__ bk,
    const float* __restrict__ bv, const int* __restrict__ mask,
    ushort* __restrict__ Qw, ushort* __restrict__ Kw, ushort* __restrict__ Vtw) {
  const int z = blockIdx.z;
  if (z == 0) {
    gemm_tile_body<2>(Abf, Wt, bq, nullptr, (void*)Qw, blockIdx.x, blockIdx.y);
  } else if (z == 1) {
    gemm_tile_body<2>(Abf + 2097152, Wt + 262144, bk, nullptr, (void*)Kw,
                      blockIdx.x, blockIdx.y);
  } else {
    gemm_tile_body<1>(Abf + 2 * 2097152, Wt + 2 * 262144, bv, mask, (void*)Vtw,
                      blockIdx.x, blockIdx.y);
  }
}

// ============================================================================
// qrel_mfma: qrel[bh][i][r] = sum_d Q[bh][i][d]*rel[r][d] (fp32 out, stride
// NREL_PAD). MFMA bf16, fragments direct from global. Grid (8, 32, 16).
// ============================================================================
__global__ __launch_bounds__(256) void qrel_mfma(const ushort* __restrict__ Qw,
                                                 const float* __restrict__ rel,
                                                 float* __restrict__ qrel) {
  const int t = threadIdx.x;
  const int lane = t & 63, wave = t >> 6;
  const int m16 = lane & 15, quad = lane >> 4;
  const int r0 = blockIdx.x * 64;
  const int i0 = blockIdx.y * 64;
  const int bh = blockIdx.z;
  const ushort* Qb = Qw + ((size_t)bh * 2048 + i0 + (wave << 4) + m16) * 64;
  bf16x8 qa0 = *(const bf16x8*)(Qb + (quad << 3));
  bf16x8 qa1 = *(const bf16x8*)(Qb + 32 + (quad << 3));

  f32x4 acc[4] = {{0.f, 0.f, 0.f, 0.f}, {0.f, 0.f, 0.f, 0.f},
                  {0.f, 0.f, 0.f, 0.f}, {0.f, 0.f, 0.f, 0.f}};
#pragma unroll
  for (int rt = 0; rt < 4; ++rt) {
    int rr = min(r0 + (rt << 4) + m16, NREL - 1);
    const float* rp = rel + (size_t)rr * 64 + (quad << 3);
    bf16x8 rf0 = pack8(*(const float4*)rp, *(const float4*)(rp + 4));
    bf16x8 rf1 = pack8(*(const float4*)(rp + 32), *(const float4*)(rp + 36));
    acc[rt] = __builtin_amdgcn_mfma_f32_16x16x32_bf16(qa0, rf0, acc[rt], 0, 0, 0);
    acc[rt] = __builtin_amdgcn_mfma_f32_16x16x32_bf16(qa1, rf1, acc[rt], 0, 0, 0);
  }
#pragma unroll
  for (int rt = 0; rt < 4; ++rt) {
    int r = r0 + (rt << 4) + m16;
    if (r < NREL_PAD) {
#pragma unroll
      for (int rg = 0; rg < 4; ++rg) {
        int i = i0 + (wave << 4) + (quad << 2) + rg;
        qrel[((size_t)bh * 2048 + i) * NREL_PAD + r] = acc[rt][rg];
      }
    }
  }
}

// ============================================================================
// qrel gather for one 64-j tile; wave-uniform clamp shortcut.
// ============================================================================
__device__ __forceinline__ void gather_qv(float qv[4][4],
                                          const float* __restrict__ qrow,
                                          int iq, int iw0, int j0, int quad) {
  if (j0 - iw0 >= 264) {  // j - i >= 249 for all pairs -> rr = 498
    float e = qrow[NREL - 1];
#pragma unroll
    for (int jt = 0; jt < 4; ++jt)
#pragma unroll
      for (int r = 0; r < 4; ++r) qv[jt][r] = e;
  } else if (iw0 - j0 >= 312) {  // i - j >= 249 for all pairs -> rr = 0
    float e = qrow[0];
#pragma unroll
    for (int jt = 0; jt < 4; ++jt)
#pragma unroll
      for (int r = 0; r < 4; ++r) qv[jt][r] = e;
  } else {
#pragma unroll
    for (int jt = 0; jt < 4; ++jt) {
#pragma unroll
      for (int r = 0; r < 4; ++r) {
        int j = j0 + (jt << 4) + (quad << 2) + r;
        int rr = min(NREL - 1, max(0, j - iq + (NREL / 2)));
        qv[jt][r] = qrow[rr];
      }
    }
  }
}

// ============================================================================
// Flash attention, MFMA bf16, swapped-operand QK^T (S^T per lane).
// Output written as bf16 (identical rounding to the downstream GEMM's old
// fragment pack — numerically equivalent, halves attn traffic).
// ============================================================================
__global__ __launch_bounds__(256) void flash_attn(
    const ushort* __restrict__ Qw, const ushort* __restrict__ Kw,
    const ushort* __restrict__ Vt, const float* __restrict__ qrel,
    const ushort* __restrict__ maskbf, ushort* __restrict__ attnbf) {
  __shared__ ushort QPs[64 * LDB];  // Q tile [i][d]; later P [i][j]
  __shared__ ushort Ks[64 * LDB];   // [j][d]
  __shared__ ushort Vs[64 * LDB];   // [d][j]
  const int t = threadIdx.x;
  const int lane = t & 63, wave = t >> 6;
  const int m16 = lane & 15, quad = lane >> 4;
  const int koff = quad << 3;
  const int i0 = blockIdx.x * 64;
  const int bh = blockIdx.y;
  const int b = bh >> 3, h = bh & 7;
  const ushort* Qb = Qw + (size_t)bh * 2048 * 64;
  const ushort* Kb = Kw + (size_t)bh * 2048 * 64;
  const ushort* Vb = Vt + (size_t)bh * 64 * 2048;
  const ushort* mbf = maskbf + b * 2048;
  const int iw0 = i0 + (wave << 4);
  const int iq = iw0 + m16;  // this lane's output row
  const float* qrow = qrel + ((size_t)bh * 2048 + iq) * NREL_PAD;

  const int row0 = t >> 3, off0 = (t & 7) << 3;
  const int row1 = (t + 256) >> 3, off1 = ((t + 256) & 7) << 3;

  // Q tile -> LDS
  *(uint4*)&QPs[row0 * LDB + off0] =
      *(const uint4*)(Qb + (size_t)(i0 + row0) * 64 + off0);
  *(uint4*)&QPs[row1 * LDB + off1] =
      *(const uint4*)(Qb + (size_t)(i0 + row1) * 64 + off1);
  __syncthreads();

  bf16x8 qa0 = *(const bf16x8*)&QPs[((wave << 4) + m16) * LDB + koff];
  bf16x8 qa1 = *(const bf16x8*)&QPs[((wave << 4) + m16) * LDB + 32 + koff];

  // ---- prologue prefetch for j0 = 0 ----
  uint4 kr0 = *(const uint4*)(Kb + (size_t)row0 * 64 + off0);
  uint4 kr1 = *(const uint4*)(Kb + (size_t)row1 * 64 + off1);
  uint4 vr0 = *(const uint4*)(Vb + (size_t)row0 * 2048 + off0);
  uint4 vr1 = *(const uint4*)(Vb + (size_t)row1 * 2048 + off1);
  bf16x8 mfr0 = *(const bf16x8*)(mbf + koff);
  bf16x8 mfr1 = *(const bf16x8*)(mbf + 32 + koff);
  float qv[4][4];
  gather_qv(qv, qrow, iq, iw0, 0, quad);

  float m_i = -INFINITY;
  f32x4 oacc[4];
  f32x4 lacc = {0.f, 0.f, 0.f, 0.f};
#pragma unroll
  for (int dt = 0; dt < 4; ++dt) oacc[dt] = (f32x4){0.f, 0.f, 0.f, 0.f};

  for (int j0 = 0; j0 < 2048; j0 += 64) {
    __syncthreads();
    *(uint4*)&Ks[row0 * LDB + off0] = kr0;
    *(uint4*)&Ks[row1 * LDB + off1] = kr1;
    *(uint4*)&Vs[row0 * LDB + off0] = vr0;
    *(uint4*)&Vs[row1 * LDB + off1] = vr1;
    __syncthreads();

    const int jn = (j0 + 64) & 2047;  // wraps on last iter (unused)
    uint4 kn0 = *(const uint4*)(Kb + (size_t)(jn + row0) * 64 + off0);
    uint4 kn1 = *(const uint4*)(Kb + (size_t)(jn + row1) * 64 + off1);
    uint4 vn0 = *(const uint4*)(Vb + (size_t)row0 * 2048 + jn + off0);
    uint4 vn1 = *(const uint4*)(Vb + (size_t)row1 * 2048 + jn + off1);
    bf16x8 mfn0 = *(const bf16x8*)(mbf + jn + koff);
    bf16x8 mfn1 = *(const bf16x8*)(mbf + jn + 32 + koff);
    float qn[4][4];
    gather_qv(qn, qrow, iq, iw0, jn, quad);

    // ---- QK^T, swapped: sacc[jt][r] = S[iq][j0 + jt*16 + quad*4 + r]
    f32x4 sacc[4];
    __builtin_amdgcn_s_setprio(1);
#pragma unroll
    for (int jt = 0; jt < 4; ++jt) {
      bf16x8 kb0 = *(const bf16x8*)&Ks[((jt << 4) + m16) * LDB + koff];
      bf16x8 kb1 = *(const bf16x8*)&Ks[((jt << 4) + m16) * LDB + 32 + koff];
      f32x4 z = {0.f, 0.f, 0.f, 0.f};
      z = __builtin_amdgcn_mfma_f32_16x16x32_bf16(kb0, qa0, z, 0, 0, 0);
      z = __builtin_amdgcn_mfma_f32_16x16x32_bf16(kb1, qa1, z, 0, 0, 0);
      sacc[jt] = z;
    }
    __builtin_amdgcn_s_setprio(0);

    float sv[4][4];
#pragma unroll
    for (int jt = 0; jt < 4; ++jt)
#pragma unroll
      for (int r = 0; r < 4; ++r)
        sv[jt][r] = sacc[jt][r] * 0.125f + qv[jt][r];

    // ---- online softmax: in-register 16-max + 2 cross-quad shfl ----
    float t0 = fmaxf(fmaxf(sv[0][0], sv[0][1]), fmaxf(sv[0][2], sv[0][3]));
    float t1 = fmaxf(fmaxf(sv[1][0], sv[1][1]), fmaxf(sv[1][2], sv[1][3]));
    float t2 = fmaxf(fmaxf(sv[2][0], sv[2][1]), fmaxf(sv[2][2], sv[2][3]));
    float t3 = fmaxf(fmaxf(sv[3][0], sv[3][1]), fmaxf(sv[3][2], sv[3][3]));
    float mx = fmaxf(fmaxf(t0, t1), fmaxf(t2, t3));
    mx = fmaxf(mx, __shfl_xor(mx, 16));
    mx = fmaxf(mx, __shfl_xor(mx, 32));
    float mnew = fmaxf(m_i, mx);
    float al = __expf(m_i - mnew);
    m_i = mnew;

    // ---- P = exp(sv - mnew), pack, store as b64 runs ----
    const int prow = ((wave << 4) + m16) * LDB;
#pragma unroll
    for (int jt = 0; jt < 4; ++jt) {
      ushort4 pk;
      pk.x = f2bf(__expf(sv[jt][0] - mnew));
      pk.y = f2bf(__expf(sv[jt][1] - mnew));
      pk.z = f2bf(__expf(sv[jt][2] - mnew));
      pk.w = f2bf(__expf(sv[jt][3] - mnew));
      *(ushort4*)&QPs[prow + (jt << 4) + (quad << 2)] = pk;
    }

#pragma unroll
    for (int dt = 0; dt < 4; ++dt)
#pragma unroll
      for (int r = 0; r < 4; ++r) oacc[dt][r] *= al;
#pragma unroll
    for (int r = 0; r < 4; ++r) lacc[r] *= al;

    __asm__ volatile("s_waitcnt lgkmcnt(0)" ::: "memory");

    bf16x8 pa0 = *(const bf16x8*)&QPs[prow + koff];
    bf16x8 pa1 = *(const bf16x8*)&QPs[prow + 32 + koff];
    __builtin_amdgcn_s_setprio(1);
    lacc = __builtin_amdgcn_mfma_f32_16x16x32_bf16(mfr0, pa0, lacc, 0, 0, 0);
    lacc = __builtin_amdgcn_mfma_f32_16x16x32_bf16(mfr1, pa1, lacc, 0, 0, 0);
#pragma unroll
    for (int dt = 0; dt < 4; ++dt) {
      bf16x8 vb0 = *(const bf16x8*)&Vs[((dt << 4) + m16) * LDB + koff];
      bf16x8 vb1 = *(const bf16x8*)&Vs[((dt << 4) + m16) * LDB + 32 + koff];
      oacc[dt] = __builtin_amdgcn_mfma_f32_16x16x32_bf16(vb0, pa0, oacc[dt], 0, 0, 0);
      oacc[dt] = __builtin_amdgcn_mfma_f32_16x16x32_bf16(vb1, pa1, oacc[dt], 0, 0, 0);
    }
    __builtin_amdgcn_s_setprio(0);

    kr0 = kn0; kr1 = kn1; vr0 = vn0; vr1 = vn1;
    mfr0 = mfn0; mfr1 = mfn1;
#pragma unroll
    for (int jt = 0; jt < 4; ++jt)
#pragma unroll
      for (int r = 0; r < 4; ++r) qv[jt][r] = qn[jt][r];
  }

  // epilogue: lane holds O[iq][d = dt*16 + quad*4 + r]; l_i = lacc[0]
  float inv = 1.0f / lacc[0];
  ushort* dst = attnbf + (size_t)(b * 2048 + iq) * 512 + h * 64;
#pragma unroll
  for (int dt = 0; dt < 4; ++dt) {
    ushort4 st;
    st.x = f2bf(oacc[dt][0] * inv);
    st.y = f2bf(oacc[dt][1] * inv);
    st.z = f2bf(oacc[dt][2] * inv);
    st.w = f2bf(oacc[dt][3] * inv);
    *(ushort4*)(dst + (dt << 4) + (quad << 2)) = st;
  }
}

// ============================================================================
extern "C" void kernel_launch(void* const* d_in, const int* in_sizes, int n_in,
                              void* d_out, int out_size, void* d_ws,
                              size_t ws_size, hipStream_t stream) {
  const float* query = (const float*)d_in[0];
  const float* key   = (const float*)d_in[1];
  const float* value = (const float*)d_in[2];
  const int*   mask  = (const int*)d_in[3];
  const float* Wq = (const float*)d_in[4];
  const float* bq = (const float*)d_in[5];
  const float* Wk = (const float*)d_in[6];
  const float* bk = (const float*)d_in[7];
  const float* Wv = (const float*)d_in[8];
  const float* bv = (const float*)d_in[9];
  const float* Wo = (const float*)d_in[10];
  const float* bo = (const float*)d_in[11];
  const float* rel = (const float*)d_in[12];

  char* w = (char*)d_ws;
  size_t off = 0;
  ushort* Qw  = (ushort*)(w + off); off += (size_t)16 * 2048 * 64 * 2;       // 4 MB
  ushort* Kw  = (ushort*)(w + off); off += (size_t)16 * 2048 * 64 * 2;       // 4 MB
  ushort* Vtw = (ushort*)(w + off); off += (size_t)16 * 64 * 2048 * 2;       // 4 MB
  ushort* Wt  = (ushort*)(w + off); off += (size_t)4 * 512 * 512 * 2;        // 2 MB
  float* qrel = (float*)(w + off);  off += (size_t)16 * 2048 * NREL_PAD * 4; // 65.5 MB
  ushort* attnbf = (ushort*)(w + off); off += (size_t)4096 * 512 * 2;        // 4 MB
  ushort* Abf = (ushort*)(w + off); off += (size_t)3 * 4096 * 512 * 2;       // 12.6 MB
  ushort* maskbf = (ushort*)(w + off); off += (size_t)2 * 2048 * 2;          // 8 KB
  float* out = (float*)d_out;

  dim3 bb(256);
  hipLaunchKernelGGL(cast_bf16, dim3(1024, 1, 3), bb, 0, stream, query, key,
                     value, Abf);
  hipLaunchKernelGGL(prep_wt, dim3(8, 8, 4), bb, 0, stream, Wq, Wk, Wv, Wo,
                     mask, Wt, maskbf);
  hipLaunchKernelGGL(gemm_qkv, dim3(8, 64, 3), bb, 0, stream, Abf, Wt, bq, bk,
                     bv, mask, Qw, Kw, Vtw);
  hipLaunchKernelGGL(qrel_mfma, dim3(8, 32, 16), bb, 0, stream, Qw, rel, qrel);
  hipLaunchKernelGGL(flash_attn, dim3(32, 16), bb, 0, stream, Qw, Kw, Vtw, qrel,
                     maskbf, attnbf);
  hipLaunchKernelGGL((gemm_tile<0>), dim3(8, 64), bb, 0, stream, attnbf,
                     Wt + 3 * 262144, bo, (void*)out);
}